// Round 12
// baseline (459.231 us; speedup 1.0000x reference)
//
#include <hip/hip_runtime.h>

#define LOSS_OFF 8388608
#define IDX_OFF  8388609

// ws layout (bytes)  (total ~1.58 MB -- within proven-safe footprint)
#define WS_SEE   0          // float[1024]
#define WS_SXX   4096       // float[32768]   -> 135168
#define WS_KEY   135168     // u64[32768]     -> 397312
#define WS_CNT   397312     // int
#define WS_LOSS  397320     // double
#define WS_WL    397328     // int[32768]     -> 528400
#define WS_EH    528448     // ushort[262144] -> 1052736
#define WS_EL    1052736    // ushort[262144] -> 1577024

#define FLT_BIG  3.402823466e+38f
#define MARGIN   1.0e-4f

typedef __attribute__((ext_vector_type(8))) short  short8v;
typedef __attribute__((ext_vector_type(4))) float  float4v;

// numpy pairwise_sum of 256 squared elements, bit-exact (round-2 notes).
__device__ __forceinline__ float np_sumsq256(const float* __restrict__ p, int stride) {
    float s[2];
#pragma unroll
    for (int half = 0; half < 2; half++) {
        const float* a = p + half * 128 * stride;
        float r[8];
#pragma unroll
        for (int l = 0; l < 8; l++) {
            float v = a[l * stride];
            float sq = v * v;
            asm volatile("" : "+v"(sq));   // forbid fma contraction
            r[l] = sq;
        }
#pragma unroll
        for (int i = 8; i < 128; i += 8) {
#pragma unroll
            for (int l = 0; l < 8; l++) {
                float v = a[(i + l) * stride];
                float sq = v * v;
                asm volatile("" : "+v"(sq));
                r[l] = r[l] + sq;
            }
        }
        s[half] = ((r[0] + r[1]) + (r[2] + r[3])) + ((r[4] + r[5]) + (r[6] + r[7]));
    }
    return s[0] + s[1];
}

__device__ __forceinline__ unsigned int f32_sortable(float m) {
    unsigned int u = __float_as_uint(m);
    return u ^ (((unsigned int)((int)u >> 31)) | 0x80000000u);
}

__device__ __forceinline__ unsigned short f2bf(float f) {      // RNE float->bf16
    unsigned int u = __float_as_uint(f);
    return (unsigned short)((u + 0x7fffu + ((u >> 16) & 1u)) >> 16);
}
__device__ __forceinline__ float bf2f(unsigned short h) {
    return __uint_as_float(((unsigned int)h) << 16);
}

// ---------------- k0: codebook ||e||^2 (np semantics) + init ----------------
__global__ __launch_bounds__(256) void k0_see(const float* __restrict__ emb,
                                              float* __restrict__ see,
                                              int* __restrict__ cnt,
                                              double* __restrict__ loss) {
    const int k = blockIdx.x * 256 + threadIdx.x;   // grid 4
    see[k] = np_sumsq256(emb + (size_t)k * 256, 1);
    if (k == 0) { *cnt = 0; *loss = 0.0; }
}

// ---------------- k_esplit: e -> bf16 hi/lo arrays [k][c] ----------------
__global__ __launch_bounds__(256) void k_esplit(const float* __restrict__ emb,
                                                unsigned short* __restrict__ ehB,
                                                unsigned short* __restrict__ elB) {
    const int i = blockIdx.x * 256 + threadIdx.x;   // grid 1024 -> 262144
    const float v = emb[i];
    const unsigned short h = f2bf(v);
    ehB[i] = h;
    elB[i] = f2bf(v - bf2f(h));                     // v-h exact (Sterbenz)
}

// ---------------- k_xsplit: x -> bf16 hi/lo transposed [n][c] + sxx ----------------
// 32 rows x 256 c per block, grid 1024. hi/lo arrays live in d_out (overwritten by k3).
__global__ __launch_bounds__(256) void k_xsplit(const float* __restrict__ x,
                                                unsigned short* __restrict__ xhT,
                                                unsigned short* __restrict__ xlT,
                                                float* __restrict__ sxx) {
    __shared__ float xs[256 * 32];
    const int t = threadIdx.x, rs = blockIdx.x;
    const int row = t & 31, cg = t >> 5;
    const int b = rs >> 5;
    const int hw0 = (rs & 31) << 5;
    const float* xb = x + (size_t)b * 262144 + hw0 + row;
#pragma unroll 4
    for (int cc = 0; cc < 32; cc++) {
        const int c = cg * 32 + cc;
        xs[c * 32 + row] = xb[(size_t)c * 1024];
    }
    __syncthreads();
    const size_t gro = ((size_t)rs * 32 + row) * 256;
#pragma unroll
    for (int q8 = 0; q8 < 4; q8++) {
        const int cb = cg * 32 + q8 * 8;
        uint4 hp, lp;
        unsigned short* hpp = (unsigned short*)&hp;
        unsigned short* lpp = (unsigned short*)&lp;
#pragma unroll
        for (int i = 0; i < 8; i++) {
            const float v = xs[(cb + i) * 32 + row];
            const unsigned short h = f2bf(v);
            hpp[i] = h;
            lpp[i] = f2bf(v - bf2f(h));
        }
        *(uint4*)(xhT + gro + cb) = hp;
        *(uint4*)(xlT + gro + cb) = lp;
    }
    if (t < 32) sxx[rs * 32 + t] = np_sumsq256(xs + t, 32);
}

// ---------------- k1: 3-product bf16 MFMA screen ----------------
// grid 1024 blocks x 1024 thr (16 waves, __launch_bounds__(1024,4) -> VGPR
// budget 128). Block = 32 rows x ALL 1024 codes; wave w: rowg=w>>3 (16 rows),
// codeg=w&7 (128 codes = 8 16x16 tiles) -> acc[8] f32x4 = 32 VGPRs (round 11's
// acc[2][8]=64 at a 64-reg budget spilled to scratch: 274 MB writes, 9% MfmaUtil).
// A-frag: row=lane&15, k(c)=8*(lane>>4)+i; B-frag: col=lane&15, same k.
// C/D: col=lane&15, row=(lane>>4)*4+j  [m89-verified].
// dot_est = xh*eh + xh*el + xl*eh in ONE fp32 accumulator; margin covers
// np two-fl-rounding slop (6.2e-5) + est error (<1e-5).
__global__ __launch_bounds__(1024, 4) void k1_mfma(
        const unsigned short* __restrict__ xhT,
        const unsigned short* __restrict__ xlT,
        const unsigned short* __restrict__ ehB,
        const unsigned short* __restrict__ elB,
        const float* __restrict__ see_g,
        unsigned long long* __restrict__ key,
        int* __restrict__ cnt, int* __restrict__ wl) {
    __shared__ unsigned long long lk1[32][8];
    __shared__ float lg1[32][8];
    __shared__ float lg2[32][8];
    const int t = threadIdx.x;
    const int w = t >> 6, l = t & 63;
    const int rowg = w >> 3, codeg = w & 7;
    const int lrow = l >> 4, lcol = l & 15;
    const int n0 = blockIdx.x * 32;

    float4v acc[8];
#pragma unroll
    for (int ct = 0; ct < 8; ct++) acc[ct] = (float4v){0.f, 0.f, 0.f, 0.f};

    const size_t aoff = (size_t)(n0 + rowg * 16 + lcol) * 256 + lrow * 8;
    const size_t boff = (size_t)(codeg * 128 + lcol) * 256 + lrow * 8;

#pragma unroll
    for (int cc = 0; cc < 8; cc++) {
        const int cb = cc * 32;
        const short8v ah = *(const short8v*)(xhT + aoff + cb);
        const short8v al = *(const short8v*)(xlT + aoff + cb);
#pragma unroll
        for (int ct = 0; ct < 8; ct++) {
            const short8v bh = *(const short8v*)(ehB + boff + (size_t)ct * 4096 + cb);
            const short8v bl = *(const short8v*)(elB + boff + (size_t)ct * 4096 + cb);
            acc[ct] = __builtin_amdgcn_mfma_f32_16x16x32_bf16(ah, bh, acc[ct], 0, 0, 0);
            acc[ct] = __builtin_amdgcn_mfma_f32_16x16x32_bf16(ah, bl, acc[ct], 0, 0, 0);
            acc[ct] = __builtin_amdgcn_mfma_f32_16x16x32_bf16(al, bh, acc[ct], 0, 0, 0);
        }
    }

    float sv[8];
#pragma unroll
    for (int ct = 0; ct < 8; ct++) sv[ct] = see_g[codeg * 128 + ct * 16 + lcol];

    // per-row top-2 of g = see - 2*dot_est  (sxx is row-constant: order-neutral)
#pragma unroll
    for (int j = 0; j < 4; j++) {
        unsigned long long K1 = ~0ull; float G1 = FLT_BIG, G2 = FLT_BIG;
#pragma unroll
        for (int ct = 0; ct < 8; ct++) {
            const float g = fmaf(-2.f, acc[ct][j], sv[ct]);
            const int k = codeg * 128 + ct * 16 + lcol;
            const unsigned long long pk =
                ((unsigned long long)f32_sortable(g) << 32) | (unsigned int)k;
            if (pk < K1) { G2 = G1; K1 = pk; G1 = g; }
            else         { G2 = fminf(G2, g); }
        }
#pragma unroll
        for (int m = 1; m < 16; m <<= 1) {
            const unsigned long long oK = __shfl_xor(K1, m, 64);
            const float oG1 = __shfl_xor(G1, m, 64);
            const float oG2 = __shfl_xor(G2, m, 64);
            if (oK < K1) { G2 = fminf(oG2, G1); K1 = oK; G1 = oG1; }
            else         { G2 = fminf(G2, oG1); }
        }
        const int rloc = rowg * 16 + lrow * 4 + j;
        if (lcol == 0) { lk1[rloc][codeg] = K1; lg1[rloc][codeg] = G1; lg2[rloc][codeg] = G2; }
    }
    __syncthreads();
    if (t < 32) {
        unsigned long long K1 = ~0ull; float G1 = FLT_BIG, G2 = FLT_BIG;
        for (int cg = 0; cg < 8; cg++) {
            const unsigned long long oK = lk1[t][cg];
            const float oG1 = lg1[t][cg], oG2 = lg2[t][cg];
            if (oK < K1) { G2 = fminf(oG2, G1); K1 = oK; G1 = oG1; }
            else         { G2 = fminf(G2, oG1); }
        }
        const int n = n0 + t;
        if (G2 - G1 > MARGIN) { key[n] = K1; }
        else { key[n] = ~0ull; wl[atomicAdd(cnt, 1)] = n; }
    }
}

// ---------------- k2r: np-exact fp32-chain rescan of ambiguous rows ----------------
// 8 rows per block, all 1024 codes; thread t handles codes t+256j. e read once/c.
__global__ __launch_bounds__(256) void k2r(const float* __restrict__ x,
                                           const float* __restrict__ emb,
                                           const float* __restrict__ see,
                                           const float* __restrict__ sxx,
                                           unsigned long long* __restrict__ key,
                                           const int* __restrict__ cnt,
                                           const int* __restrict__ wl) {
    const int t = threadIdx.x;
    const int total = *cnt;
    const float* e0 = emb + (size_t)t * 256;
    const float* e1 = e0 + 65536;
    const float* e2 = e1 + 65536;
    const float* e3 = e2 + 65536;
    for (int base = blockIdx.x * 8; base < total; base += 128 * 8) {
        int nrow[8]; float sx8[8];
#pragma unroll
        for (int r = 0; r < 8; r++) {
            int idx = base + r; if (idx >= total) idx = base;   // benign dup
            const int n = wl[idx];
            nrow[r] = n; sx8[r] = sxx[n];
        }
        float d[8][4];
#pragma unroll
        for (int r = 0; r < 8; r++)
#pragma unroll
            for (int j = 0; j < 4; j++) d[r][j] = 0.f;
        for (int c = 0; c < 256; c++) {
            const float ev0 = e0[c], ev1 = e1[c], ev2 = e2[c], ev3 = e3[c];
#pragma unroll
            for (int r = 0; r < 8; r++) {
                const int n = nrow[r];
                const float xv = x[(size_t)(n >> 10) * 262144 + (size_t)c * 1024 + (n & 1023)];
                d[r][0] = fmaf(xv, ev0, d[r][0]);
                d[r][1] = fmaf(xv, ev1, d[r][1]);
                d[r][2] = fmaf(xv, ev2, d[r][2]);
                d[r][3] = fmaf(xv, ev3, d[r][3]);
            }
        }
#pragma unroll
        for (int r = 0; r < 8; r++) {
            unsigned long long best = ~0ull;
#pragma unroll
            for (int j = 0; j < 4; j++) {
                const float q = fmaf(-2.f, d[r][j], sx8[r]) + see[t + 256 * j];
                const unsigned long long pk =
                    ((unsigned long long)f32_sortable(q) << 32) | (unsigned int)(t + 256 * j);
                best = pk < best ? pk : best;
            }
            atomicMin(&key[nrow[r]], best);
        }
    }
}

// ---------------- k3: gather quantized + loss partials + indices ----------------
__global__ __launch_bounds__(256) void k3_out(const float* __restrict__ x,
                                              const float* __restrict__ emb,
                                              const unsigned long long* __restrict__ key,
                                              float* __restrict__ dout,
                                              double* __restrict__ loss) {
    __shared__ float elds[32][257];
    __shared__ int   idxs[32];
    __shared__ float red[256];
    const int t  = threadIdx.x;
    const int bh = blockIdx.x;
    const int b = bh >> 5, h = bh & 31;
    if (t < 32) idxs[t] = (int)(key[(bh << 5) + t] & 0xffffffffull);
    __syncthreads();
    for (int r = 0; r < 32; r++) elds[r][t] = emb[(size_t)idxs[r] * 256 + t];
    __syncthreads();
    const int w = t & 31, cg = t >> 5;
    const size_t base = (size_t)b * 262144 + (size_t)(h * 32 + w);
    float acc = 0.f;
#pragma unroll 4
    for (int s = 0; s < 32; s++) {
        const int c = (cg << 5) + s;
        const float q  = elds[w][c];
        const float xv = x[base + (size_t)c * 1024];
        dout[base + (size_t)c * 1024] = q;
        const float d = q - xv;
        acc = fmaf(d, d, acc);
    }
    red[t] = acc;
    __syncthreads();
    for (int s = 128; s > 0; s >>= 1) {
        if (t < s) red[t] += red[t + s];
        __syncthreads();
    }
    if (t == 0) atomicAdd(loss, (double)red[0]);
    if (t < 32) dout[IDX_OFF + (bh << 5) + t] = (float)idxs[t];
}

// ---------------- k4: finalize loss ----------------
__global__ void k4_fin(const double* __restrict__ loss, float* __restrict__ dout) {
    dout[LOSS_OFF] = (float)(1.25 * (*loss) / 8388608.0);
}

extern "C" void kernel_launch(void* const* d_in, const int* in_sizes, int n_in,
                              void* d_out, int out_size, void* d_ws, size_t ws_size,
                              hipStream_t stream) {
    const float* x   = (const float*)d_in[0];
    const float* emb = (const float*)d_in[1];
    float* dout = (float*)d_out;
    char* ws = (char*)d_ws;
    float*  see  = (float*)(ws + WS_SEE);
    float*  sxx  = (float*)(ws + WS_SXX);
    unsigned long long* key = (unsigned long long*)(ws + WS_KEY);
    int*    cnt  = (int*)(ws + WS_CNT);
    double* loss = (double*)(ws + WS_LOSS);
    int*    wl   = (int*)(ws + WS_WL);
    unsigned short* ehB = (unsigned short*)(ws + WS_EH);
    unsigned short* elB = (unsigned short*)(ws + WS_EL);
    // bf16-split transposed x parked in d_out's quantized region (k3 overwrites later)
    unsigned short* xhT = (unsigned short*)d_out;
    unsigned short* xlT = xhT + 8388608;

    k0_see  <<<4,    256, 0, stream>>>(emb, see, cnt, loss);
    k_esplit<<<1024, 256, 0, stream>>>(emb, ehB, elB);
    k_xsplit<<<1024, 256, 0, stream>>>(x, xhT, xlT, sxx);
    k1_mfma <<<1024, 1024, 0, stream>>>(xhT, xlT, ehB, elB, see, key, cnt, wl);
    k2r     <<<128,  256, 0, stream>>>(x, emb, see, sxx, key, cnt, wl);
    k3_out  <<<1024, 256, 0, stream>>>(x, emb, key, dout, loss);
    k4_fin  <<<1,      1, 0, stream>>>(loss, dout);
}

// Round 13
// 277.453 us; speedup vs baseline: 1.6552x; 1.6552x over previous
//
#include <hip/hip_runtime.h>

#define LOSS_OFF 8388608
#define IDX_OFF  8388609

// ws layout (bytes)  (total ~1.58 MB)
#define WS_SEE   0          // float[1024]
#define WS_SXX   4096       // float[32768]   -> 135168
#define WS_KEY   135168     // u64[32768]     -> 397312
#define WS_CNT   397312     // int
#define WS_LOSS  397320     // double
#define WS_WL    397328     // int[32768]     -> 528400
#define WS_EP    528448     // packed E frags: 8*8*8*2*64*16B = 1 MB -> 1577024

#define FLT_BIG  3.402823466e+38f
#define MARGIN   1.0e-4f

typedef __attribute__((ext_vector_type(8))) short  short8v;
typedef __attribute__((ext_vector_type(4))) float  float4v;

// numpy pairwise_sum of 256 squared elements, bit-exact (round-2 notes).
__device__ __forceinline__ float np_sumsq256(const float* __restrict__ p, int stride) {
    float s[2];
#pragma unroll
    for (int half = 0; half < 2; half++) {
        const float* a = p + half * 128 * stride;
        float r[8];
#pragma unroll
        for (int l = 0; l < 8; l++) {
            float v = a[l * stride];
            float sq = v * v;
            asm volatile("" : "+v"(sq));   // forbid fma contraction
            r[l] = sq;
        }
#pragma unroll
        for (int i = 8; i < 128; i += 8) {
#pragma unroll
            for (int l = 0; l < 8; l++) {
                float v = a[(i + l) * stride];
                float sq = v * v;
                asm volatile("" : "+v"(sq));
                r[l] = r[l] + sq;
            }
        }
        s[half] = ((r[0] + r[1]) + (r[2] + r[3])) + ((r[4] + r[5]) + (r[6] + r[7]));
    }
    return s[0] + s[1];
}

__device__ __forceinline__ unsigned int f32_sortable(float m) {
    unsigned int u = __float_as_uint(m);
    return u ^ (((unsigned int)((int)u >> 31)) | 0x80000000u);
}

__device__ __forceinline__ unsigned short f2bf(float f) {      // RNE float->bf16
    unsigned int u = __float_as_uint(f);
    return (unsigned short)((u + 0x7fffu + ((u >> 16) & 1u)) >> 16);
}
__device__ __forceinline__ float bf2f(unsigned short h) {
    return __uint_as_float(((unsigned int)h) << 16);
}

// ---------------- k0: codebook ||e||^2 (np semantics) + init ----------------
__global__ __launch_bounds__(256) void k0_see(const float* __restrict__ emb,
                                              float* __restrict__ see,
                                              int* __restrict__ cnt,
                                              double* __restrict__ loss) {
    const int k = blockIdx.x * 256 + threadIdx.x;   // grid 4
    see[k] = np_sumsq256(emb + (size_t)k * 256, 1);
    if (k == 0) { *cnt = 0; *loss = 0.0; }
}

// ---------------- k_epack: emb -> MFMA-fragment-packed bf16 hi/lo ----------------
// ebP chunk index idx = [codeg(8)][cc(8)][ct(8)][ph(2)][l(64)], 16B per chunk.
// chunk value elem i = split(emb[codeg*128+ct*16+(l&15)][cc*32+(l>>4)*8+i]).
// k1's B-load for (codeg,cc,ct,ph) is then 64 lanes x 16B CONTIGUOUS (1 KB).
__global__ __launch_bounds__(256) void k_epack(const float* __restrict__ emb,
                                               unsigned short* __restrict__ ebP) {
    const int idx = blockIdx.x * 256 + threadIdx.x;   // grid 256 -> 65536 chunks
    const int l  = idx & 63;
    const int ph = (idx >> 6) & 1;
    const int ct = (idx >> 7) & 7;
    const int cc = (idx >> 10) & 7;
    const int cg = (idx >> 13) & 7;
    const int row = cg * 128 + ct * 16 + (l & 15);
    const int col = cc * 32 + (l >> 4) * 8;
    const float* src = emb + (size_t)row * 256 + col;
    uint4 out;
    unsigned short* op = (unsigned short*)&out;
#pragma unroll
    for (int i = 0; i < 8; i++) {
        const float v = src[i];
        const unsigned short h = f2bf(v);
        op[i] = ph ? f2bf(v - bf2f(h)) : h;      // v-h exact (Sterbenz)
    }
    *(uint4*)(ebP + (size_t)idx * 8) = out;
}

// ---------------- k_xpack: x -> MFMA-fragment-packed bf16 hi/lo + sxx ----------------
// axP chunk index per row-set rs: [cc(8)][rowg(2)][ph(2)][l(64)], 16B each (32 KB/rs).
// chunk value elem i = split(x_row(n0+rowg*16+(l&15), c=cc*32+(l>>4)*8+i)).
// Lives in d_out (32 MB), overwritten by k3 later.
__global__ __launch_bounds__(256) void k_xpack(const float* __restrict__ x,
                                               unsigned short* __restrict__ axP,
                                               float* __restrict__ sxx) {
    __shared__ float xs[256 * 33];
    const int t = threadIdx.x, rs = blockIdx.x;     // grid 1024, 32 rows each
    const int row = t & 31, cg = t >> 5;
    const int b = rs >> 5;
    const int hw0 = (rs & 31) << 5;
    const float* xb = x + (size_t)b * 262144 + hw0 + row;
#pragma unroll 4
    for (int cc2 = 0; cc2 < 32; cc2++) {
        const int c = cg * 32 + cc2;
        xs[c * 33 + row] = xb[(size_t)c * 1024];
    }
    __syncthreads();
#pragma unroll
    for (int ii = 0; ii < 4; ii++) {
        const int ci = ii * 256 + t;                // chunk-pair 0..1023
        const int l = ci & 63;
        const int rowg = (ci >> 6) & 1;
        const int cc = ci >> 7;
        const int r = rowg * 16 + (l & 15);
        const int c0 = cc * 32 + (l >> 4) * 8;
        uint4 hp, lp;
        unsigned short* hpp = (unsigned short*)&hp;
        unsigned short* lpp = (unsigned short*)&lp;
#pragma unroll
        for (int i = 0; i < 8; i++) {
            const float v = xs[(c0 + i) * 33 + r];
            const unsigned short h = f2bf(v);
            hpp[i] = h;
            lpp[i] = f2bf(v - bf2f(h));
        }
        const size_t base = ((size_t)rs * 8 + cc) * 2 + rowg;   // [rs][cc][rowg]
        *(uint4*)(axP + ((base * 2 + 0) * 64 + l) * 8) = hp;
        *(uint4*)(axP + ((base * 2 + 1) * 64 + l) * 8) = lp;
    }
    if (t < 32) sxx[rs * 32 + t] = np_sumsq256(xs + t, 33);
}

// ---------------- k1: 3-product bf16 MFMA screen (packed operands) ----------------
// grid 1024 x 1024 thr (16 waves, launch_bounds(1024,4)). Block = 32 rows x 1024
// codes; wave w: rowg=w>>3, codeg=w&7 -> acc[8] f32x4 = 32 VGPR (no spill, r12).
// ALL loads are base + l*16B: contiguous 1 KB per wave-instruction (round 12's
// 512B-lane-stride gathers + 8KB tile aliasing camped L2 channels: 283us, 7% util).
// dot_est = xh*eh + xh*el + xl*eh in ONE fp32 acc; margin covers np two-fl
// rounding slop (6.2e-5) + est error (<1e-5). C/D: col=lane&15, row=(lane>>4)*4+j.
__global__ __launch_bounds__(1024, 4) void k1_mfma(
        const unsigned short* __restrict__ axP,
        const unsigned short* __restrict__ ebP,
        const float* __restrict__ see_g,
        unsigned long long* __restrict__ key,
        int* __restrict__ cnt, int* __restrict__ wl) {
    __shared__ unsigned long long lk1[32][8];
    __shared__ float lg1[32][8];
    __shared__ float lg2[32][8];
    const int t = threadIdx.x;
    const int w = t >> 6, l = t & 63;
    const int rowg = w >> 3, codeg = w & 7;
    const int lrow = l >> 4, lcol = l & 15;
    const int rb = blockIdx.x;
    const int n0 = rb * 32;

    float4v acc[8];
#pragma unroll
    for (int ct = 0; ct < 8; ct++) acc[ct] = (float4v){0.f, 0.f, 0.f, 0.f};

#pragma unroll
    for (int cc = 0; cc < 8; cc++) {
        const size_t ab = ((((size_t)rb * 8 + cc) * 2 + rowg) * 2) * 512 + (size_t)l * 8;
        const short8v ah = *(const short8v*)(axP + ab);
        const short8v al = *(const short8v*)(axP + ab + 512);
#pragma unroll
        for (int ct = 0; ct < 8; ct++) {
            const size_t bb = ((((size_t)codeg * 8 + cc) * 8 + ct) * 2) * 512 + (size_t)l * 8;
            const short8v bh = *(const short8v*)(ebP + bb);
            const short8v bl = *(const short8v*)(ebP + bb + 512);
            acc[ct] = __builtin_amdgcn_mfma_f32_16x16x32_bf16(ah, bh, acc[ct], 0, 0, 0);
            acc[ct] = __builtin_amdgcn_mfma_f32_16x16x32_bf16(ah, bl, acc[ct], 0, 0, 0);
            acc[ct] = __builtin_amdgcn_mfma_f32_16x16x32_bf16(al, bh, acc[ct], 0, 0, 0);
        }
    }

    float sv[8];
#pragma unroll
    for (int ct = 0; ct < 8; ct++) sv[ct] = see_g[codeg * 128 + ct * 16 + lcol];

    // per-row top-2 of g = see - 2*dot_est  (sxx is row-constant: order-neutral)
#pragma unroll
    for (int j = 0; j < 4; j++) {
        unsigned long long K1 = ~0ull; float G1 = FLT_BIG, G2 = FLT_BIG;
#pragma unroll
        for (int ct = 0; ct < 8; ct++) {
            const float g = fmaf(-2.f, acc[ct][j], sv[ct]);
            const int k = codeg * 128 + ct * 16 + lcol;
            const unsigned long long pk =
                ((unsigned long long)f32_sortable(g) << 32) | (unsigned int)k;
            if (pk < K1) { G2 = G1; K1 = pk; G1 = g; }
            else         { G2 = fminf(G2, g); }
        }
#pragma unroll
        for (int m = 1; m < 16; m <<= 1) {
            const unsigned long long oK = __shfl_xor(K1, m, 64);
            const float oG1 = __shfl_xor(G1, m, 64);
            const float oG2 = __shfl_xor(G2, m, 64);
            if (oK < K1) { G2 = fminf(oG2, G1); K1 = oK; G1 = oG1; }
            else         { G2 = fminf(G2, oG1); }
        }
        const int rloc = rowg * 16 + lrow * 4 + j;
        if (lcol == 0) { lk1[rloc][codeg] = K1; lg1[rloc][codeg] = G1; lg2[rloc][codeg] = G2; }
    }
    __syncthreads();
    if (t < 32) {
        unsigned long long K1 = ~0ull; float G1 = FLT_BIG, G2 = FLT_BIG;
        for (int cg = 0; cg < 8; cg++) {
            const unsigned long long oK = lk1[t][cg];
            const float oG1 = lg1[t][cg], oG2 = lg2[t][cg];
            if (oK < K1) { G2 = fminf(oG2, G1); K1 = oK; G1 = oG1; }
            else         { G2 = fminf(G2, oG1); }
        }
        const int n = n0 + t;
        if (G2 - G1 > MARGIN) { key[n] = K1; }
        else { key[n] = ~0ull; wl[atomicAdd(cnt, 1)] = n; }
    }
}

// ---------------- k2r: np-exact fp32-chain rescan of ambiguous rows ----------------
__global__ __launch_bounds__(256) void k2r(const float* __restrict__ x,
                                           const float* __restrict__ emb,
                                           const float* __restrict__ see,
                                           const float* __restrict__ sxx,
                                           unsigned long long* __restrict__ key,
                                           const int* __restrict__ cnt,
                                           const int* __restrict__ wl) {
    const int t = threadIdx.x;
    const int total = *cnt;
    const float* e0 = emb + (size_t)t * 256;
    const float* e1 = e0 + 65536;
    const float* e2 = e1 + 65536;
    const float* e3 = e2 + 65536;
    for (int base = blockIdx.x * 8; base < total; base += 128 * 8) {
        int nrow[8]; float sx8[8];
#pragma unroll
        for (int r = 0; r < 8; r++) {
            int idx = base + r; if (idx >= total) idx = base;   // benign dup
            const int n = wl[idx];
            nrow[r] = n; sx8[r] = sxx[n];
        }
        float d[8][4];
#pragma unroll
        for (int r = 0; r < 8; r++)
#pragma unroll
            for (int j = 0; j < 4; j++) d[r][j] = 0.f;
        for (int c = 0; c < 256; c++) {
            const float ev0 = e0[c], ev1 = e1[c], ev2 = e2[c], ev3 = e3[c];
#pragma unroll
            for (int r = 0; r < 8; r++) {
                const int n = nrow[r];
                const float xv = x[(size_t)(n >> 10) * 262144 + (size_t)c * 1024 + (n & 1023)];
                d[r][0] = fmaf(xv, ev0, d[r][0]);
                d[r][1] = fmaf(xv, ev1, d[r][1]);
                d[r][2] = fmaf(xv, ev2, d[r][2]);
                d[r][3] = fmaf(xv, ev3, d[r][3]);
            }
        }
#pragma unroll
        for (int r = 0; r < 8; r++) {
            unsigned long long best = ~0ull;
#pragma unroll
            for (int j = 0; j < 4; j++) {
                const float q = fmaf(-2.f, d[r][j], sx8[r]) + see[t + 256 * j];
                const unsigned long long pk =
                    ((unsigned long long)f32_sortable(q) << 32) | (unsigned int)(t + 256 * j);
                best = pk < best ? pk : best;
            }
            atomicMin(&key[nrow[r]], best);
        }
    }
}

// ---------------- k3: gather quantized + loss partials + indices ----------------
__global__ __launch_bounds__(256) void k3_out(const float* __restrict__ x,
                                              const float* __restrict__ emb,
                                              const unsigned long long* __restrict__ key,
                                              float* __restrict__ dout,
                                              double* __restrict__ loss) {
    __shared__ float elds[32][257];
    __shared__ int   idxs[32];
    __shared__ float red[256];
    const int t  = threadIdx.x;
    const int bh = blockIdx.x;
    const int b = bh >> 5, h = bh & 31;
    if (t < 32) idxs[t] = (int)(key[(bh << 5) + t] & 0xffffffffull);
    __syncthreads();
    for (int r = 0; r < 32; r++) elds[r][t] = emb[(size_t)idxs[r] * 256 + t];
    __syncthreads();
    const int w = t & 31, cg = t >> 5;
    const size_t base = (size_t)b * 262144 + (size_t)(h * 32 + w);
    float acc = 0.f;
#pragma unroll 4
    for (int s = 0; s < 32; s++) {
        const int c = (cg << 5) + s;
        const float q  = elds[w][c];
        const float xv = x[base + (size_t)c * 1024];
        dout[base + (size_t)c * 1024] = q;
        const float d = q - xv;
        acc = fmaf(d, d, acc);
    }
    red[t] = acc;
    __syncthreads();
    for (int s = 128; s > 0; s >>= 1) {
        if (t < s) red[t] += red[t + s];
        __syncthreads();
    }
    if (t == 0) atomicAdd(loss, (double)red[0]);
    if (t < 32) dout[IDX_OFF + (bh << 5) + t] = (float)idxs[t];
}

// ---------------- k4: finalize loss ----------------
__global__ void k4_fin(const double* __restrict__ loss, float* __restrict__ dout) {
    dout[LOSS_OFF] = (float)(1.25 * (*loss) / 8388608.0);
}

extern "C" void kernel_launch(void* const* d_in, const int* in_sizes, int n_in,
                              void* d_out, int out_size, void* d_ws, size_t ws_size,
                              hipStream_t stream) {
    const float* x   = (const float*)d_in[0];
    const float* emb = (const float*)d_in[1];
    float* dout = (float*)d_out;
    char* ws = (char*)d_ws;
    float*  see  = (float*)(ws + WS_SEE);
    float*  sxx  = (float*)(ws + WS_SXX);
    unsigned long long* key = (unsigned long long*)(ws + WS_KEY);
    int*    cnt  = (int*)(ws + WS_CNT);
    double* loss = (double*)(ws + WS_LOSS);
    int*    wl   = (int*)(ws + WS_WL);
    unsigned short* ebP = (unsigned short*)(ws + WS_EP);
    // packed A fragments parked in d_out (32 MB), overwritten by k3 later
    unsigned short* axP = (unsigned short*)d_out;

    k0_see <<<4,    256, 0, stream>>>(emb, see, cnt, loss);
    k_epack<<<256,  256, 0, stream>>>(emb, ebP);
    k_xpack<<<1024, 256, 0, stream>>>(x, axP, sxx);
    k1_mfma<<<1024, 1024, 0, stream>>>(axP, ebP, see, key, cnt, wl);
    k2r    <<<128,  256, 0, stream>>>(x, emb, see, sxx, key, cnt, wl);
    k3_out <<<1024, 256, 0, stream>>>(x, emb, key, dout, loss);
    k4_fin <<<1,      1, 0, stream>>>(loss, dout);
}

// Round 14
// 236.590 us; speedup vs baseline: 1.9410x; 1.1727x over previous
//
#include <hip/hip_runtime.h>

#define LOSS_OFF 8388608
#define IDX_OFF  8388609

// ws layout (bytes)  (total ~1.58 MB)
#define WS_SEE   0          // float[1024]
#define WS_SXX   4096       // float[32768]   -> 135168
#define WS_KEY   135168     // u64[32768]     -> 397312
#define WS_CNT   397312     // int
#define WS_LOSS  397320     // double
#define WS_WL    397328     // int[32768]     -> 528400
#define WS_EP    528448     // packed E frags (1 MB) during k1; REUSED as eT[c][k] (1 MB) after k1

#define FLT_BIG  3.402823466e+38f
#define MARGIN   1.0e-4f

typedef __attribute__((ext_vector_type(8))) short  short8v;
typedef __attribute__((ext_vector_type(4))) float  float4v;

// numpy pairwise_sum of 256 squared elements, bit-exact (round-2 notes).
__device__ __forceinline__ float np_sumsq256(const float* __restrict__ p, int stride) {
    float s[2];
#pragma unroll
    for (int half = 0; half < 2; half++) {
        const float* a = p + half * 128 * stride;
        float r[8];
#pragma unroll
        for (int l = 0; l < 8; l++) {
            float v = a[l * stride];
            float sq = v * v;
            asm volatile("" : "+v"(sq));   // forbid fma contraction
            r[l] = sq;
        }
#pragma unroll
        for (int i = 8; i < 128; i += 8) {
#pragma unroll
            for (int l = 0; l < 8; l++) {
                float v = a[(i + l) * stride];
                float sq = v * v;
                asm volatile("" : "+v"(sq));
                r[l] = r[l] + sq;
            }
        }
        s[half] = ((r[0] + r[1]) + (r[2] + r[3])) + ((r[4] + r[5]) + (r[6] + r[7]));
    }
    return s[0] + s[1];
}

__device__ __forceinline__ unsigned int f32_sortable(float m) {
    unsigned int u = __float_as_uint(m);
    return u ^ (((unsigned int)((int)u >> 31)) | 0x80000000u);
}

__device__ __forceinline__ unsigned short f2bf(float f) {      // RNE float->bf16
    unsigned int u = __float_as_uint(f);
    return (unsigned short)((u + 0x7fffu + ((u >> 16) & 1u)) >> 16);
}
__device__ __forceinline__ float bf2f(unsigned short h) {
    return __uint_as_float(((unsigned int)h) << 16);
}

// ---------------- k0: codebook ||e||^2 (np semantics) + init ----------------
__global__ __launch_bounds__(256) void k0_see(const float* __restrict__ emb,
                                              float* __restrict__ see,
                                              int* __restrict__ cnt,
                                              double* __restrict__ loss) {
    const int k = blockIdx.x * 256 + threadIdx.x;   // grid 4
    see[k] = np_sumsq256(emb + (size_t)k * 256, 1);
    if (k == 0) { *cnt = 0; *loss = 0.0; }
}

// ---------------- k_epack: emb -> MFMA-fragment-packed bf16 hi/lo ----------------
// ebP chunk idx = [codeg(8)][cc(8)][ct(8)][ph(2)][l(64)], 16B per chunk.
__global__ __launch_bounds__(256) void k_epack(const float* __restrict__ emb,
                                               unsigned short* __restrict__ ebP) {
    const int idx = blockIdx.x * 256 + threadIdx.x;   // grid 256 -> 65536 chunks
    const int l  = idx & 63;
    const int ph = (idx >> 6) & 1;
    const int ct = (idx >> 7) & 7;
    const int cc = (idx >> 10) & 7;
    const int cg = (idx >> 13) & 7;
    const int row = cg * 128 + ct * 16 + (l & 15);
    const int col = cc * 32 + (l >> 4) * 8;
    const float* src = emb + (size_t)row * 256 + col;
    uint4 out;
    unsigned short* op = (unsigned short*)&out;
#pragma unroll
    for (int i = 0; i < 8; i++) {
        const float v = src[i];
        const unsigned short h = f2bf(v);
        op[i] = ph ? f2bf(v - bf2f(h)) : h;      // v-h exact (Sterbenz)
    }
    *(uint4*)(ebP + (size_t)idx * 8) = out;
}

// ---------------- k_et: transpose codebook -> eT[c][k] (runs AFTER k1) ----------------
// Writes over the ebP region (dead after k1_mfma). Proven in rounds 8-10.
__global__ __launch_bounds__(256) void k_et(const float* __restrict__ emb,
                                            float* __restrict__ eT) {
    __shared__ float T[256][17];
    const int t  = threadIdx.x;
    const int k0 = blockIdx.x << 4;                 // grid 64
    const int kr = t >> 4, cs = (t & 15) << 4;
#pragma unroll
    for (int j = 0; j < 4; j++) {
        const float4 v = *(const float4*)(emb + (size_t)(k0 + kr) * 256 + cs + j * 4);
        T[cs + j * 4 + 0][kr] = v.x;
        T[cs + j * 4 + 1][kr] = v.y;
        T[cs + j * 4 + 2][kr] = v.z;
        T[cs + j * 4 + 3][kr] = v.w;
    }
    __syncthreads();
    float* dst = eT + (size_t)t * 1024 + k0;
#pragma unroll
    for (int j = 0; j < 4; j++) {
        float4 v;
        v.x = T[t][j * 4 + 0]; v.y = T[t][j * 4 + 1];
        v.z = T[t][j * 4 + 2]; v.w = T[t][j * 4 + 3];
        *(float4*)(dst + j * 4) = v;
    }
}

// ---------------- k_xpack: x -> MFMA-fragment-packed bf16 hi/lo + sxx ----------------
__global__ __launch_bounds__(256) void k_xpack(const float* __restrict__ x,
                                               unsigned short* __restrict__ axP,
                                               float* __restrict__ sxx) {
    __shared__ float xs[256 * 33];
    const int t = threadIdx.x, rs = blockIdx.x;     // grid 1024, 32 rows each
    const int row = t & 31, cg = t >> 5;
    const int b = rs >> 5;
    const int hw0 = (rs & 31) << 5;
    const float* xb = x + (size_t)b * 262144 + hw0 + row;
#pragma unroll 4
    for (int cc2 = 0; cc2 < 32; cc2++) {
        const int c = cg * 32 + cc2;
        xs[c * 33 + row] = xb[(size_t)c * 1024];
    }
    __syncthreads();
#pragma unroll
    for (int ii = 0; ii < 4; ii++) {
        const int ci = ii * 256 + t;                // chunk-pair 0..1023
        const int l = ci & 63;
        const int rowg = (ci >> 6) & 1;
        const int cc = ci >> 7;
        const int r = rowg * 16 + (l & 15);
        const int c0 = cc * 32 + (l >> 4) * 8;
        uint4 hp, lp;
        unsigned short* hpp = (unsigned short*)&hp;
        unsigned short* lpp = (unsigned short*)&lp;
#pragma unroll
        for (int i = 0; i < 8; i++) {
            const float v = xs[(c0 + i) * 33 + r];
            const unsigned short h = f2bf(v);
            hpp[i] = h;
            lpp[i] = f2bf(v - bf2f(h));
        }
        const size_t base = ((size_t)rs * 8 + cc) * 2 + rowg;   // [rs][cc][rowg]
        *(uint4*)(axP + ((base * 2 + 0) * 64 + l) * 8) = hp;
        *(uint4*)(axP + ((base * 2 + 1) * 64 + l) * 8) = lp;
    }
    if (t < 32) sxx[rs * 32 + t] = np_sumsq256(xs + t, 33);
}

// ---------------- k1: 3-product bf16 MFMA screen (packed operands) ----------------
__global__ __launch_bounds__(1024, 4) void k1_mfma(
        const unsigned short* __restrict__ axP,
        const unsigned short* __restrict__ ebP,
        const float* __restrict__ see_g,
        unsigned long long* __restrict__ key,
        int* __restrict__ cnt, int* __restrict__ wl) {
    __shared__ unsigned long long lk1[32][8];
    __shared__ float lg1[32][8];
    __shared__ float lg2[32][8];
    const int t = threadIdx.x;
    const int w = t >> 6, l = t & 63;
    const int rowg = w >> 3, codeg = w & 7;
    const int lrow = l >> 4, lcol = l & 15;
    const int rb = blockIdx.x;
    const int n0 = rb * 32;

    float4v acc[8];
#pragma unroll
    for (int ct = 0; ct < 8; ct++) acc[ct] = (float4v){0.f, 0.f, 0.f, 0.f};

#pragma unroll
    for (int cc = 0; cc < 8; cc++) {
        const size_t ab = ((((size_t)rb * 8 + cc) * 2 + rowg) * 2) * 512 + (size_t)l * 8;
        const short8v ah = *(const short8v*)(axP + ab);
        const short8v al = *(const short8v*)(axP + ab + 512);
#pragma unroll
        for (int ct = 0; ct < 8; ct++) {
            const size_t bb = ((((size_t)codeg * 8 + cc) * 8 + ct) * 2) * 512 + (size_t)l * 8;
            const short8v bh = *(const short8v*)(ebP + bb);
            const short8v bl = *(const short8v*)(ebP + bb + 512);
            acc[ct] = __builtin_amdgcn_mfma_f32_16x16x32_bf16(ah, bh, acc[ct], 0, 0, 0);
            acc[ct] = __builtin_amdgcn_mfma_f32_16x16x32_bf16(ah, bl, acc[ct], 0, 0, 0);
            acc[ct] = __builtin_amdgcn_mfma_f32_16x16x32_bf16(al, bh, acc[ct], 0, 0, 0);
        }
    }

    float sv[8];
#pragma unroll
    for (int ct = 0; ct < 8; ct++) sv[ct] = see_g[codeg * 128 + ct * 16 + lcol];

#pragma unroll
    for (int j = 0; j < 4; j++) {
        unsigned long long K1 = ~0ull; float G1 = FLT_BIG, G2 = FLT_BIG;
#pragma unroll
        for (int ct = 0; ct < 8; ct++) {
            const float g = fmaf(-2.f, acc[ct][j], sv[ct]);
            const int k = codeg * 128 + ct * 16 + lcol;
            const unsigned long long pk =
                ((unsigned long long)f32_sortable(g) << 32) | (unsigned int)k;
            if (pk < K1) { G2 = G1; K1 = pk; G1 = g; }
            else         { G2 = fminf(G2, g); }
        }
#pragma unroll
        for (int m = 1; m < 16; m <<= 1) {
            const unsigned long long oK = __shfl_xor(K1, m, 64);
            const float oG1 = __shfl_xor(G1, m, 64);
            const float oG2 = __shfl_xor(G2, m, 64);
            if (oK < K1) { G2 = fminf(oG2, G1); K1 = oK; G1 = oG1; }
            else         { G2 = fminf(G2, oG1); }
        }
        const int rloc = rowg * 16 + lrow * 4 + j;
        if (lcol == 0) { lk1[rloc][codeg] = K1; lg1[rloc][codeg] = G1; lg2[rloc][codeg] = G2; }
    }
    __syncthreads();
    if (t < 32) {
        unsigned long long K1 = ~0ull; float G1 = FLT_BIG, G2 = FLT_BIG;
        for (int cg = 0; cg < 8; cg++) {
            const unsigned long long oK = lk1[t][cg];
            const float oG1 = lg1[t][cg], oG2 = lg2[t][cg];
            if (oK < K1) { G2 = fminf(oG2, G1); K1 = oK; G1 = oG1; }
            else         { G2 = fminf(G2, oG1); }
        }
        const int n = n0 + t;
        if (G2 - G1 > MARGIN) { key[n] = K1; }
        else { key[n] = ~0ull; wl[atomicAdd(cnt, 1)] = n; }
    }
}

// ---------------- k2r: np-exact fp32-chain rescan (coalesced via eT) ----------------
// 8 rows per block batch (grid-stride). Thread t owns codes {t, 256+t, 512+t, 768+t}.
// e-reads: eT[c*1024 + t + 256j] -- lanes consecutive => fully coalesced (round 13's
// emb column-gather at 1KB lane stride serialized ~64 lines/instr: 124us, all idle).
// x staged once per batch into LDS; broadcast reads. Same fp32 chain c=0..255.
__global__ __launch_bounds__(256) void k2r(const float* __restrict__ x,
                                           const float* __restrict__ eT,
                                           const float* __restrict__ see,
                                           const float* __restrict__ sxx,
                                           unsigned long long* __restrict__ key,
                                           const int* __restrict__ cnt,
                                           const int* __restrict__ wl) {
    __shared__ float xs[8][264];
    const int t = threadIdx.x;
    const int total = *cnt;
    for (int base = blockIdx.x * 8; base < total; base += 128 * 8) {
        int nrow[8]; float sx8[8];
#pragma unroll
        for (int r = 0; r < 8; r++) {
            int idx = base + r; if (idx >= total) idx = total - 1;   // benign dup
            const int n = wl[idx];
            nrow[r] = n; sx8[r] = sxx[n];
        }
        __syncthreads();                 // prior batch's xs reads done
#pragma unroll
        for (int r = 0; r < 8; r++) {
            const int n = nrow[r];
            xs[r][t] = x[(size_t)(n >> 10) * 262144 + (size_t)t * 1024 + (n & 1023)];
        }
        __syncthreads();
        float d[8][4];
#pragma unroll
        for (int r = 0; r < 8; r++)
#pragma unroll
            for (int j = 0; j < 4; j++) d[r][j] = 0.f;
#pragma unroll 4
        for (int c = 0; c < 256; c++) {
            float ev[4];
#pragma unroll
            for (int j = 0; j < 4; j++) ev[j] = eT[(size_t)c * 1024 + t + 256 * j];
#pragma unroll
            for (int r = 0; r < 8; r++) {
                const float xv = xs[r][c];
                d[r][0] = fmaf(xv, ev[0], d[r][0]);
                d[r][1] = fmaf(xv, ev[1], d[r][1]);
                d[r][2] = fmaf(xv, ev[2], d[r][2]);
                d[r][3] = fmaf(xv, ev[3], d[r][3]);
            }
        }
#pragma unroll
        for (int r = 0; r < 8; r++) {
            unsigned long long best = ~0ull;
#pragma unroll
            for (int j = 0; j < 4; j++) {
                const float q = fmaf(-2.f, d[r][j], sx8[r]) + see[t + 256 * j];
                const unsigned long long pk =
                    ((unsigned long long)f32_sortable(q) << 32) | (unsigned int)(t + 256 * j);
                best = pk < best ? pk : best;
            }
            atomicMin(&key[nrow[r]], best);
        }
    }
}

// ---------------- k3: gather quantized + loss partials + indices ----------------
__global__ __launch_bounds__(256) void k3_out(const float* __restrict__ x,
                                              const float* __restrict__ emb,
                                              const unsigned long long* __restrict__ key,
                                              float* __restrict__ dout,
                                              double* __restrict__ loss) {
    __shared__ float elds[32][257];
    __shared__ int   idxs[32];
    __shared__ float red[256];
    const int t  = threadIdx.x;
    const int bh = blockIdx.x;
    const int b = bh >> 5, h = bh & 31;
    if (t < 32) idxs[t] = (int)(key[(bh << 5) + t] & 0xffffffffull);
    __syncthreads();
    for (int r = 0; r < 32; r++) elds[r][t] = emb[(size_t)idxs[r] * 256 + t];
    __syncthreads();
    const int w = t & 31, cg = t >> 5;
    const size_t base = (size_t)b * 262144 + (size_t)(h * 32 + w);
    float acc = 0.f;
#pragma unroll 4
    for (int s = 0; s < 32; s++) {
        const int c = (cg << 5) + s;
        const float q  = elds[w][c];
        const float xv = x[base + (size_t)c * 1024];
        dout[base + (size_t)c * 1024] = q;
        const float d = q - xv;
        acc = fmaf(d, d, acc);
    }
    red[t] = acc;
    __syncthreads();
    for (int s = 128; s > 0; s >>= 1) {
        if (t < s) red[t] += red[t + s];
        __syncthreads();
    }
    if (t == 0) atomicAdd(loss, (double)red[0]);
    if (t < 32) dout[IDX_OFF + (bh << 5) + t] = (float)idxs[t];
}

// ---------------- k4: finalize loss ----------------
__global__ void k4_fin(const double* __restrict__ loss, float* __restrict__ dout) {
    dout[LOSS_OFF] = (float)(1.25 * (*loss) / 8388608.0);
}

extern "C" void kernel_launch(void* const* d_in, const int* in_sizes, int n_in,
                              void* d_out, int out_size, void* d_ws, size_t ws_size,
                              hipStream_t stream) {
    const float* x   = (const float*)d_in[0];
    const float* emb = (const float*)d_in[1];
    float* dout = (float*)d_out;
    char* ws = (char*)d_ws;
    float*  see  = (float*)(ws + WS_SEE);
    float*  sxx  = (float*)(ws + WS_SXX);
    unsigned long long* key = (unsigned long long*)(ws + WS_KEY);
    int*    cnt  = (int*)(ws + WS_CNT);
    double* loss = (double*)(ws + WS_LOSS);
    int*    wl   = (int*)(ws + WS_WL);
    unsigned short* ebP = (unsigned short*)(ws + WS_EP);
    float*  eT   = (float*)(ws + WS_EP);      // same region: ebP dead after k1
    // packed A fragments parked in d_out (32 MB), overwritten by k3 later
    unsigned short* axP = (unsigned short*)d_out;

    k0_see <<<4,    256, 0, stream>>>(emb, see, cnt, loss);
    k_epack<<<256,  256, 0, stream>>>(emb, ebP);
    k_xpack<<<1024, 256, 0, stream>>>(x, axP, sxx);
    k1_mfma<<<1024, 1024, 0, stream>>>(axP, ebP, see, key, cnt, wl);
    k_et   <<<64,   256, 0, stream>>>(emb, eT);          // overwrites ebP region
    k2r    <<<128,  256, 0, stream>>>(x, eT, see, sxx, key, cnt, wl);
    k3_out <<<1024, 256, 0, stream>>>(x, emb, key, dout, loss);
    k4_fin <<<1,      1, 0, stream>>>(loss, dout);
}